// Round 1
// baseline (22842.360 us; speedup 1.0000x reference)
//
#include <hip/hip_runtime.h>
#include <math.h>

// Problem constants
#define BB   32
#define NN   197
#define CC   768
#define HH   12
#define DD   64
#define KWW  197
#define HIDD 3072
#define NL   12
#define RR   (BB*NN)      // 6304 rows
#define BHH  (BB*HH)      // 384 batch*head

// ---------------------------------------------------------------------------
// LayerNorm over C=768. One block (256 thr) per row; 3 elems/thread.
__global__ void ln768_kernel(const float* __restrict__ in, const float* __restrict__ g,
                             const float* __restrict__ be, float* __restrict__ out) {
    int row = blockIdx.x;
    const float* x = in + (size_t)row * CC;
    float* o = out + (size_t)row * CC;
    int t = threadIdx.x;
    float v0 = x[t], v1 = x[t+256], v2 = x[t+512];
    float s = v0+v1+v2;
    float q = v0*v0+v1*v1+v2*v2;
    for (int off = 1; off < 64; off <<= 1) {
        s += __shfl_xor(s, off, 64);
        q += __shfl_xor(q, off, 64);
    }
    __shared__ float sh[8];
    int wv = t >> 6, ln = t & 63;
    if (ln == 0) { sh[wv] = s; sh[4+wv] = q; }
    __syncthreads();
    s = sh[0]+sh[1]+sh[2]+sh[3];
    q = sh[4]+sh[5]+sh[6]+sh[7];
    float mu  = s * (1.0f/CC);
    float var = q * (1.0f/CC) - mu*mu;
    float rs  = rsqrtf(var + 1e-5f);
    o[t]     = (v0-mu)*rs*g[t]     + be[t];
    o[t+256] = (v1-mu)*rs*g[t+256] + be[t+256];
    o[t+512] = (v2-mu)*rs*g[t+512] + be[t+512];
}

// ---------------------------------------------------------------------------
// Fused LayerNorm + softmax over KW=197. One wave per row, 4 waves/block.
__global__ void lnsoftmax_kernel(float* __restrict__ S, const float* __restrict__ g,
                                 const float* __restrict__ be) {
    int row  = blockIdx.x * 4 + (threadIdx.x >> 6);
    int lane = threadIdx.x & 63;
    float* p = S + (size_t)row * KWW;
    float v[4];
    float s = 0.f, q = 0.f;
    #pragma unroll
    for (int t = 0; t < 4; t++) {
        int k = lane + t*64;
        float x = (k < KWW) ? p[k] : 0.f;
        v[t] = x; s += x; q += x*x;
    }
    for (int o = 1; o < 64; o <<= 1) { s += __shfl_xor(s, o, 64); q += __shfl_xor(q, o, 64); }
    float mu  = s * (1.0f/KWW);
    float var = q * (1.0f/KWW) - mu*mu;
    float rs  = rsqrtf(var + 1e-5f);
    float mx = -1e30f;
    #pragma unroll
    for (int t = 0; t < 4; t++) {
        int k = lane + t*64;
        if (k < KWW) { v[t] = (v[t]-mu)*rs*g[k] + be[k]; mx = fmaxf(mx, v[t]); }
    }
    for (int o = 1; o < 64; o <<= 1) mx = fmaxf(mx, __shfl_xor(mx, o, 64));
    float se = 0.f;
    #pragma unroll
    for (int t = 0; t < 4; t++) {
        int k = lane + t*64;
        if (k < KWW) { v[t] = expf(v[t]-mx); se += v[t]; }
    }
    for (int o = 1; o < 64; o <<= 1) se += __shfl_xor(se, o, 64);
    float inv = 1.0f / se;
    #pragma unroll
    for (int t = 0; t < 4; t++) {
        int k = lane + t*64;
        if (k < KWW) p[k] = v[t]*inv;
    }
}

// ---------------------------------------------------------------------------
// Generic tiled fp32 GEMM, C = A@B (+epilogue). 64x64 tile, 16 K-step,
// 256 threads, 4x4 acc per thread. Optional batch (blockIdx.z) strides.
// EPI: 0 = store; 1 = +bias(col) store; 2 = +bias gelu store; 3 = +bias accumulate
template<int EPI>
__global__ void gemm_kernel(const float* __restrict__ A, long Az,
                            const float* __restrict__ Bm,
                            const float* __restrict__ bias,
                            float* __restrict__ Cm, long Cz,
                            int M, int Nd, int K)
{
    const float* Ab = A  + (size_t)blockIdx.z * Az;
    float*       Cb = Cm + (size_t)blockIdx.z * Cz;
    __shared__ __align__(16) float As[16][68];
    __shared__ __align__(16) float Bs[16][68];
    int tid = threadIdx.x;
    int tx = tid & 15, ty = tid >> 4;
    int bm = blockIdx.y * 64, bn = blockIdx.x * 64;
    float acc[4][4] = {};
    for (int k0 = 0; k0 < K; k0 += 16) {
        #pragma unroll
        for (int i = tid; i < 1024; i += 256) {
            int m = i >> 4, kk = i & 15;
            float va = 0.f;
            if (bm+m < M && k0+kk < K) va = Ab[(size_t)(bm+m)*K + k0+kk];
            As[kk][m] = va;
            int kb = i >> 6, nb = i & 63;
            float vb = 0.f;
            if (k0+kb < K && bn+nb < Nd) vb = Bm[(size_t)(k0+kb)*Nd + bn+nb];
            Bs[kb][nb] = vb;
        }
        __syncthreads();
        #pragma unroll
        for (int kk = 0; kk < 16; kk++) {
            float4 a  = *(const float4*)&As[kk][ty*4];
            float4 bv = *(const float4*)&Bs[kk][tx*4];
            float aa[4] = {a.x,a.y,a.z,a.w};
            float bb[4] = {bv.x,bv.y,bv.z,bv.w};
            #pragma unroll
            for (int i = 0; i < 4; i++)
                #pragma unroll
                for (int j = 0; j < 4; j++) acc[i][j] += aa[i]*bb[j];
        }
        __syncthreads();
    }
    #pragma unroll
    for (int i = 0; i < 4; i++) {
        int m = bm + ty*4 + i;
        if (m >= M) continue;
        #pragma unroll
        for (int j = 0; j < 4; j++) {
            int n = bn + tx*4 + j;
            if (n >= Nd) continue;
            float v = acc[i][j];
            if (EPI >= 1) v += bias[n];
            if (EPI == 2) v = 0.5f*v*(1.0f+erff(v*0.70710678118f));
            if (EPI == 3) Cb[(size_t)m*Nd + n] += v;
            else          Cb[(size_t)m*Nd + n] = v;
        }
    }
}

// ---------------------------------------------------------------------------
// S1[bh,i,j] = scale * sum_d q[b,i,h,d]*k[b,j,h,d].  q/k strided in qkv buffer.
__global__ void qk_kernel(const float* __restrict__ qkv, float* __restrict__ S1) {
    int bh = blockIdx.z; int b = bh / HH, h = bh % HH;
    const float* Qb = qkv + (size_t)b*NN*3*CC + (size_t)h*DD;
    const float* Kb = Qb + CC;
    int bi = blockIdx.y * 64, bj = blockIdx.x * 64;
    __shared__ __align__(16) float As[16][68];
    __shared__ __align__(16) float Bs[16][68];
    int tid = threadIdx.x;
    int tx = tid & 15, ty = tid >> 4;
    float acc[4][4] = {};
    for (int k0 = 0; k0 < DD; k0 += 16) {
        #pragma unroll
        for (int i = tid; i < 1024; i += 256) {
            int m = i >> 4, kk = i & 15;
            float va = 0.f, vb = 0.f;
            if (bi+m < NN) va = Qb[(size_t)(bi+m)*3*CC + k0+kk];
            if (bj+m < NN) vb = Kb[(size_t)(bj+m)*3*CC + k0+kk];
            As[kk][m] = va;
            Bs[kk][m] = vb;
        }
        __syncthreads();
        #pragma unroll
        for (int kk = 0; kk < 16; kk++) {
            float4 a  = *(const float4*)&As[kk][ty*4];
            float4 bv = *(const float4*)&Bs[kk][tx*4];
            float aa[4] = {a.x,a.y,a.z,a.w};
            float bb[4] = {bv.x,bv.y,bv.z,bv.w};
            #pragma unroll
            for (int i = 0; i < 4; i++)
                #pragma unroll
                for (int j = 0; j < 4; j++) acc[i][j] += aa[i]*bb[j];
        }
        __syncthreads();
    }
    #pragma unroll
    for (int i = 0; i < 4; i++) {
        int m = bi + ty*4 + i; if (m >= NN) continue;
        #pragma unroll
        for (int j = 0; j < 4; j++) {
            int n = bj + tx*4 + j; if (n >= NN) continue;
            S1[((size_t)bh*NN + m)*KWW + n] = acc[i][j]*0.125f;
        }
    }
}

// ---------------------------------------------------------------------------
// y[bh,k,d] = sum_n P[bh,n,k] * v[b,n,h,d]   (P = post-softmax S2)
__global__ void yv_kernel(const float* __restrict__ S, const float* __restrict__ qkv,
                          float* __restrict__ y) {
    int bh = blockIdx.y; int b = bh / HH, h = bh % HH;
    const float* A = S + (size_t)bh*NN*KWW;                       // [n][k]
    const float* V = qkv + (size_t)b*NN*3*CC + 2*CC + (size_t)h*DD; // row stride 3C
    float* Cy = y + (size_t)bh*KWW*DD;
    int bm = blockIdx.x * 64;   // k-tile
    __shared__ __align__(16) float As[16][68];  // As[nn][m]=A[n0+nn][bm+m]
    __shared__ __align__(16) float Bs[16][68];
    int tid = threadIdx.x; int tx = tid & 15, ty = tid >> 4;
    float acc[4][4] = {};
    for (int n0 = 0; n0 < NN; n0 += 16) {
        #pragma unroll
        for (int i = tid; i < 1024; i += 256) {
            int nn = i >> 6, m = i & 63;
            float va = 0.f, vb = 0.f;
            if (n0+nn < NN && bm+m < KWW) va = A[(size_t)(n0+nn)*KWW + bm+m];
            if (n0+nn < NN)               vb = V[(size_t)(n0+nn)*3*CC + m];
            As[nn][m] = va;
            Bs[nn][m] = vb;
        }
        __syncthreads();
        #pragma unroll
        for (int kk = 0; kk < 16; kk++) {
            float4 a  = *(const float4*)&As[kk][ty*4];
            float4 bv = *(const float4*)&Bs[kk][tx*4];
            float aa[4] = {a.x,a.y,a.z,a.w};
            float bb[4] = {bv.x,bv.y,bv.z,bv.w};
            #pragma unroll
            for (int i = 0; i < 4; i++)
                #pragma unroll
                for (int j = 0; j < 4; j++) acc[i][j] += aa[i]*bb[j];
        }
        __syncthreads();
    }
    #pragma unroll
    for (int i = 0; i < 4; i++) {
        int m = bm + ty*4 + i; if (m >= KWW) continue;
        #pragma unroll
        for (int j = 0; j < 4; j++) Cy[(size_t)m*DD + tx*4 + j] = acc[i][j];
    }
}

// ---------------------------------------------------------------------------
// x1[b,n,h*64+d] += sum_k y[bh,k,d]*fc2_w[k,n] + fc2_b[n]
__global__ void fc2_kernel(const float* __restrict__ y, const float* __restrict__ w,
                           const float* __restrict__ bias, float* __restrict__ x1) {
    int bh = blockIdx.y; int b = bh / HH, h = bh % HH;
    const float* Y = y + (size_t)bh*KWW*DD;     // [k][d]
    float* Cx = x1 + (size_t)b*NN*CC + (size_t)h*DD; // row n stride C
    int bm = blockIdx.x * 64;   // n-token tile
    __shared__ __align__(16) float As[16][68];  // As[kk][m]=w[k0+kk][bm+m]
    __shared__ __align__(16) float Bs[16][68];
    int tid = threadIdx.x; int tx = tid & 15, ty = tid >> 4;
    float acc[4][4] = {};
    for (int k0 = 0; k0 < KWW; k0 += 16) {
        #pragma unroll
        for (int i = tid; i < 1024; i += 256) {
            int kk = i >> 6, m = i & 63;
            float va = 0.f, vb = 0.f;
            if (k0+kk < KWW && bm+m < NN) va = w[(size_t)(k0+kk)*NN + bm+m];
            if (k0+kk < KWW)              vb = Y[(size_t)(k0+kk)*DD + m];
            As[kk][m] = va;
            Bs[kk][m] = vb;
        }
        __syncthreads();
        #pragma unroll
        for (int kk = 0; kk < 16; kk++) {
            float4 a  = *(const float4*)&As[kk][ty*4];
            float4 bv = *(const float4*)&Bs[kk][tx*4];
            float aa[4] = {a.x,a.y,a.z,a.w};
            float bb[4] = {bv.x,bv.y,bv.z,bv.w};
            #pragma unroll
            for (int i = 0; i < 4; i++)
                #pragma unroll
                for (int j = 0; j < 4; j++) acc[i][j] += aa[i]*bb[j];
        }
        __syncthreads();
    }
    #pragma unroll
    for (int i = 0; i < 4; i++) {
        int m = bm + ty*4 + i; if (m >= NN) continue;
        float bv = bias[m];
        #pragma unroll
        for (int j = 0; j < 4; j++) Cx[(size_t)m*CC + tx*4 + j] += acc[i][j] + bv;
    }
}

// ---------------------------------------------------------------------------
__global__ void init_kernel(const float* __restrict__ x, float* __restrict__ x1,
                            float* __restrict__ x2, int n) {
    int i = blockIdx.x*256 + threadIdx.x;
    if (i < n) { float v = x[i]; x1[i] = v; x2[i] = v; }
}
__global__ void final_kernel(const float* __restrict__ x1, const float* __restrict__ x2,
                             float* __restrict__ o, int n) {
    int i = blockIdx.x*256 + threadIdx.x;
    if (i < n) o[i] = 0.5f*(x1[i]+x2[i]);
}

// ---------------------------------------------------------------------------
extern "C" void kernel_launch(void* const* d_in, const int* in_sizes, int n_in,
                              void* d_out, int out_size, void* d_ws, size_t ws_size,
                              hipStream_t stream) {
    const float* x     = (const float*)d_in[0];
    const float* qkv_w = (const float*)d_in[1];
    const float* fc_w  = (const float*)d_in[2];
    const float* fc_b  = (const float*)d_in[3];
    const float* alng  = (const float*)d_in[4];
    const float* alnb  = (const float*)d_in[5];
    const float* fc2w  = (const float*)d_in[6];
    const float* fc2b  = (const float*)d_in[7];
    const float* w1    = (const float*)d_in[8];
    const float* b1    = (const float*)d_in[9];
    const float* w2    = (const float*)d_in[10];
    const float* b2    = (const float*)d_in[11];
    const float* flng  = (const float*)d_in[12];
    const float* flnb  = (const float*)d_in[13];
    const float* glng  = (const float*)d_in[14];
    const float* glnb  = (const float*)d_in[15];
    float* out = (float*)d_out;

    float* ws = (float*)d_ws;
    size_t off = 0;
    float* x1   = ws + off; off += (size_t)RR*CC;
    float* x2   = ws + off; off += (size_t)RR*CC;
    float* lnb  = ws + off; off += (size_t)RR*CC;      // also reused as y (same size)
    float* qkvb = ws + off; off += (size_t)RR*3*CC;
    float* S1   = ws + off; off += (size_t)BHH*NN*KWW;
    float* S2   = ws + off; off += (size_t)BHH*NN*KWW;
    float* yb   = lnb;   // alias: y live only yv->fc2, lnb live only ln->gemm
    float* hid  = S1;    // alias: hid (19.4M floats) fits in S1+S2 (29.8M floats)

    const int nel = RR*CC;
    init_kernel<<<(nel+255)/256, 256, 0, stream>>>(x, x1, x2, nel);

    for (int l = 0; l < NL; l++) {
        // --- attention branch: y1 = x1 + attn(LN(x2)) ---
        ln768_kernel<<<RR, 256, 0, stream>>>(x2, flng + l*CC, flnb + l*CC, lnb);
        gemm_kernel<0><<<dim3(36, 99, 1), 256, 0, stream>>>(
            lnb, 0, qkv_w, nullptr, qkvb, 0, RR, 3*CC, CC);
        qk_kernel<<<dim3(4, 4, BHH), 256, 0, stream>>>(qkvb, S1);
        gemm_kernel<1><<<dim3(4, 4, BHH), 256, 0, stream>>>(
            S1, (long)NN*KWW, fc_w, fc_b, S2, (long)NN*KWW, NN, KWW, NN);
        lnsoftmax_kernel<<<(BHH*NN)/4, 256, 0, stream>>>(S2, alng, alnb);
        yv_kernel<<<dim3(4, BHH), 256, 0, stream>>>(S2, qkvb, yb);
        fc2_kernel<<<dim3(4, BHH), 256, 0, stream>>>(yb, fc2w, fc2b, x1);
        // --- mlp branch: y2 = x2 + mlp(LN(y1)) ---
        ln768_kernel<<<RR, 256, 0, stream>>>(x1, glng + l*CC, glnb + l*CC, lnb);
        gemm_kernel<2><<<dim3(48, 99, 1), 256, 0, stream>>>(
            lnb, 0, w1, b1, hid, 0, RR, HIDD, CC);
        gemm_kernel<3><<<dim3(12, 99, 1), 256, 0, stream>>>(
            hid, 0, w2, b2, x2, 0, RR, CC, HIDD);
    }
    final_kernel<<<(nel+255)/256, 256, 0, stream>>>(x1, x2, out, nel);
}

// Round 2
// 7958.512 us; speedup vs baseline: 2.8702x; 2.8702x over previous
//
#include <hip/hip_runtime.h>
#include <math.h>

// Problem constants
#define BB   32
#define NN   197
#define CC   768
#define HH   12
#define DD   64
#define KWW  197
#define HIDD 3072
#define NL   12
#define RR   (BB*NN)      // 6304 rows
#define BHH  (BB*HH)      // 384 batch*head

typedef __attribute__((ext_vector_type(8))) short short8;
typedef __attribute__((ext_vector_type(4))) float floatx4;

__device__ __forceinline__ unsigned short f2bf(float f) {
    unsigned int u = __float_as_uint(f);
    u += 0x7fff + ((u >> 16) & 1);          // round-to-nearest-even
    return (unsigned short)(u >> 16);
}

// ---------------------------------------------------------------------------
// LayerNorm over C=768 -> bf16 output. One block (256 thr) per row.
__global__ void ln768_kernel(const float* __restrict__ in, const float* __restrict__ g,
                             const float* __restrict__ be, unsigned short* __restrict__ out) {
    int row = blockIdx.x;
    const float* x = in + (size_t)row * CC;
    unsigned short* o = out + (size_t)row * CC;
    int t = threadIdx.x;
    float v0 = x[t], v1 = x[t+256], v2 = x[t+512];
    float s = v0+v1+v2;
    float q = v0*v0+v1*v1+v2*v2;
    for (int off = 1; off < 64; off <<= 1) {
        s += __shfl_xor(s, off, 64);
        q += __shfl_xor(q, off, 64);
    }
    __shared__ float sh[8];
    int wv = t >> 6, ln = t & 63;
    if (ln == 0) { sh[wv] = s; sh[4+wv] = q; }
    __syncthreads();
    s = sh[0]+sh[1]+sh[2]+sh[3];
    q = sh[4]+sh[5]+sh[6]+sh[7];
    float mu  = s * (1.0f/CC);
    float var = q * (1.0f/CC) - mu*mu;
    float rs  = rsqrtf(var + 1e-5f);
    o[t]     = f2bf((v0-mu)*rs*g[t]     + be[t]);
    o[t+256] = f2bf((v1-mu)*rs*g[t+256] + be[t+256]);
    o[t+512] = f2bf((v2-mu)*rs*g[t+512] + be[t+512]);
}

// ---------------------------------------------------------------------------
// Transpose + cast fp32 [K][Nd] -> bf16 [Nd][K]
__global__ void transpose_cast(const float* __restrict__ in, unsigned short* __restrict__ out,
                               int K, int Nd) {
    __shared__ float tile[32][33];
    int n0 = blockIdx.x*32, k0 = blockIdx.y*32;
    int tx = threadIdx.x & 31, ty = threadIdx.x >> 5;   // 32 x 8
    #pragma unroll
    for (int i = 0; i < 4; i++) {
        int k = k0 + ty + i*8;
        tile[ty + i*8][tx] = (k < K && n0+tx < Nd) ? in[(size_t)k*Nd + n0 + tx] : 0.f;
    }
    __syncthreads();
    #pragma unroll
    for (int i = 0; i < 4; i++) {
        int n = n0 + ty + i*8;
        if (n < Nd && k0 + tx < K) out[(size_t)n*K + k0 + tx] = f2bf(tile[tx][ty + i*8]);
    }
}

// ---------------------------------------------------------------------------
// bf16 MFMA GEMM: C = A(bf16,[M][K]) @ Bt(bf16,[Nd][K])^T. 128x128 tile, BK=32,
// 4 waves each computing a 64x64 subtile with 4x4 of 16x16x32 MFMAs.
// Staging via global_load_lds width=16 (wave-uniform LDS base + lane*16).
// EPI: 0 = store fp32; 2 = +bias exact-GELU store bf16; 3 = +bias accumulate fp32
template<int EPI>
__global__ __launch_bounds__(256) void gemm_bf16(
    const unsigned short* __restrict__ A, const unsigned short* __restrict__ Bt,
    const float* __restrict__ bias, float* __restrict__ Cf, unsigned short* __restrict__ Cb,
    int M, int Nd, int K)
{
    __shared__ unsigned short As[128*32];
    __shared__ unsigned short Bs[128*32];
    int tid  = threadIdx.x;
    int wv   = tid >> 6, lane = tid & 63;
    int wm   = wv >> 1, wn = wv & 1;
    int bm   = blockIdx.y * 128, bn = blockIdx.x * 128;
    int quad = lane >> 4, mrow = lane & 15;
    int srow = lane >> 2;            // staging: 4 lanes per 32-elem row
    int skof = (lane & 3) * 8;       // 8 bf16 = 16B per lane
    floatx4 acc[4][4];
    #pragma unroll
    for (int i = 0; i < 4; i++)
        #pragma unroll
        for (int j = 0; j < 4; j++) acc[i][j] = (floatx4){0.f,0.f,0.f,0.f};

    for (int k0 = 0; k0 < K; k0 += 32) {
        #pragma unroll
        for (int i = 0; i < 2; i++) {
            int r  = wv*32 + i*16 + srow;          // row within 128-tile
            int gr = bm + r; if (gr > M-1) gr = M-1;   // clamp; garbage rows masked on write
            __builtin_amdgcn_global_load_lds(
                (const __attribute__((address_space(1))) void*)(A + (size_t)gr*K + k0 + skof),
                (__attribute__((address_space(3))) void*)(As + (wv*32 + i*16)*32),
                16, 0, 0);
            __builtin_amdgcn_global_load_lds(
                (const __attribute__((address_space(1))) void*)(Bt + (size_t)(bn + r)*K + k0 + skof),
                (__attribute__((address_space(3))) void*)(Bs + (wv*32 + i*16)*32),
                16, 0, 0);
        }
        __syncthreads();   // compiler drains vmcnt before s_barrier -> staging visible
        short8 af[4], bf[4];
        #pragma unroll
        for (int mi = 0; mi < 4; mi++)
            af[mi] = *(const short8*)&As[(wm*64 + mi*16 + mrow)*32 + quad*8];
        #pragma unroll
        for (int ni = 0; ni < 4; ni++)
            bf[ni] = *(const short8*)&Bs[(wn*64 + ni*16 + mrow)*32 + quad*8];
        #pragma unroll
        for (int mi = 0; mi < 4; mi++)
            #pragma unroll
            for (int ni = 0; ni < 4; ni++)
                acc[mi][ni] = __builtin_amdgcn_mfma_f32_16x16x32_bf16(af[mi], bf[ni], acc[mi][ni], 0, 0, 0);
        __syncthreads();   // all waves done reading LDS before next overwrite
    }

    #pragma unroll
    for (int mi = 0; mi < 4; mi++) {
        int row0 = bm + wm*64 + mi*16 + quad*4;
        #pragma unroll
        for (int ni = 0; ni < 4; ni++) {
            int col = bn + wn*64 + ni*16 + mrow;
            float bv = (EPI >= 1) ? bias[col] : 0.f;
            #pragma unroll
            for (int r = 0; r < 4; r++) {
                int row = row0 + r;
                if (row >= M) continue;
                float v = acc[mi][ni][r] + bv;
                if (EPI == 2) {
                    v = 0.5f*v*(1.0f + erff(v*0.70710678118f));
                    Cb[(size_t)row*Nd + col] = f2bf(v);
                } else if (EPI == 3) {
                    Cf[(size_t)row*Nd + col] += v;
                } else {
                    Cf[(size_t)row*Nd + col] = v;
                }
            }
        }
    }
}

// ---------------------------------------------------------------------------
// Fused LayerNorm + softmax over KW=197. One wave per row, 4 waves/block.
__global__ void lnsoftmax_kernel(float* __restrict__ S, const float* __restrict__ g,
                                 const float* __restrict__ be) {
    int row  = blockIdx.x * 4 + (threadIdx.x >> 6);
    int lane = threadIdx.x & 63;
    float* p = S + (size_t)row * KWW;
    float v[4];
    float s = 0.f, q = 0.f;
    #pragma unroll
    for (int t = 0; t < 4; t++) {
        int k = lane + t*64;
        float x = (k < KWW) ? p[k] : 0.f;
        v[t] = x; s += x; q += x*x;
    }
    for (int o = 1; o < 64; o <<= 1) { s += __shfl_xor(s, o, 64); q += __shfl_xor(q, o, 64); }
    float mu  = s * (1.0f/KWW);
    float var = q * (1.0f/KWW) - mu*mu;
    float rs  = rsqrtf(var + 1e-5f);
    float mx = -1e30f;
    #pragma unroll
    for (int t = 0; t < 4; t++) {
        int k = lane + t*64;
        if (k < KWW) { v[t] = (v[t]-mu)*rs*g[k] + be[k]; mx = fmaxf(mx, v[t]); }
    }
    for (int o = 1; o < 64; o <<= 1) mx = fmaxf(mx, __shfl_xor(mx, o, 64));
    float se = 0.f;
    #pragma unroll
    for (int t = 0; t < 4; t++) {
        int k = lane + t*64;
        if (k < KWW) { v[t] = expf(v[t]-mx); se += v[t]; }
    }
    for (int o = 1; o < 64; o <<= 1) se += __shfl_xor(se, o, 64);
    float inv = 1.0f / se;
    #pragma unroll
    for (int t = 0; t < 4; t++) {
        int k = lane + t*64;
        if (k < KWW) p[k] = v[t]*inv;
    }
}

// ---------------------------------------------------------------------------
// Generic tiled fp32 GEMM (kept for small attention GEMMs). EPI 1 = +bias store.
template<int EPI>
__global__ void gemm_kernel(const float* __restrict__ A, long Az,
                            const float* __restrict__ Bm,
                            const float* __restrict__ bias,
                            float* __restrict__ Cm, long Cz,
                            int M, int Nd, int K)
{
    const float* Ab = A  + (size_t)blockIdx.z * Az;
    float*       Cb = Cm + (size_t)blockIdx.z * Cz;
    __shared__ __align__(16) float As[16][68];
    __shared__ __align__(16) float Bs[16][68];
    int tid = threadIdx.x;
    int tx = tid & 15, ty = tid >> 4;
    int bm = blockIdx.y * 64, bn = blockIdx.x * 64;
    float acc[4][4] = {};
    for (int k0 = 0; k0 < K; k0 += 16) {
        #pragma unroll
        for (int i = tid; i < 1024; i += 256) {
            int m = i >> 4, kk = i & 15;
            float va = 0.f;
            if (bm+m < M && k0+kk < K) va = Ab[(size_t)(bm+m)*K + k0+kk];
            As[kk][m] = va;
            int kb = i >> 6, nb = i & 63;
            float vb = 0.f;
            if (k0+kb < K && bn+nb < Nd) vb = Bm[(size_t)(k0+kb)*Nd + bn+nb];
            Bs[kb][nb] = vb;
        }
        __syncthreads();
        #pragma unroll
        for (int kk = 0; kk < 16; kk++) {
            float4 a  = *(const float4*)&As[kk][ty*4];
            float4 bv = *(const float4*)&Bs[kk][tx*4];
            float aa[4] = {a.x,a.y,a.z,a.w};
            float bb[4] = {bv.x,bv.y,bv.z,bv.w};
            #pragma unroll
            for (int i = 0; i < 4; i++)
                #pragma unroll
                for (int j = 0; j < 4; j++) acc[i][j] += aa[i]*bb[j];
        }
        __syncthreads();
    }
    #pragma unroll
    for (int i = 0; i < 4; i++) {
        int m = bm + ty*4 + i;
        if (m >= M) continue;
        #pragma unroll
        for (int j = 0; j < 4; j++) {
            int n = bn + tx*4 + j;
            if (n >= Nd) continue;
            float v = acc[i][j];
            if (EPI >= 1) v += bias[n];
            Cb[(size_t)m*Nd + n] = v;
        }
    }
}

// ---------------------------------------------------------------------------
// S1[bh,i,j] = scale * sum_d q[b,i,h,d]*k[b,j,h,d].  q/k strided in qkv buffer.
__global__ void qk_kernel(const float* __restrict__ qkv, float* __restrict__ S1) {
    int bh = blockIdx.z; int b = bh / HH, h = bh % HH;
    const float* Qb = qkv + (size_t)b*NN*3*CC + (size_t)h*DD;
    const float* Kb = Qb + CC;
    int bi = blockIdx.y * 64, bj = blockIdx.x * 64;
    __shared__ __align__(16) float As[16][68];
    __shared__ __align__(16) float Bs[16][68];
    int tid = threadIdx.x;
    int tx = tid & 15, ty = tid >> 4;
    float acc[4][4] = {};
    for (int k0 = 0; k0 < DD; k0 += 16) {
        #pragma unroll
        for (int i = tid; i < 1024; i += 256) {
            int m = i >> 4, kk = i & 15;
            float va = 0.f, vb = 0.f;
            if (bi+m < NN) va = Qb[(size_t)(bi+m)*3*CC + k0+kk];
            if (bj+m < NN) vb = Kb[(size_t)(bj+m)*3*CC + k0+kk];
            As[kk][m] = va;
            Bs[kk][m] = vb;
        }
        __syncthreads();
        #pragma unroll
        for (int kk = 0; kk < 16; kk++) {
            float4 a  = *(const float4*)&As[kk][ty*4];
            float4 bv = *(const float4*)&Bs[kk][tx*4];
            float aa[4] = {a.x,a.y,a.z,a.w};
            float bb[4] = {bv.x,bv.y,bv.z,bv.w};
            #pragma unroll
            for (int i = 0; i < 4; i++)
                #pragma unroll
                for (int j = 0; j < 4; j++) acc[i][j] += aa[i]*bb[j];
        }
        __syncthreads();
    }
    #pragma unroll
    for (int i = 0; i < 4; i++) {
        int m = bi + ty*4 + i; if (m >= NN) continue;
        #pragma unroll
        for (int j = 0; j < 4; j++) {
            int n = bj + tx*4 + j; if (n >= NN) continue;
            S1[((size_t)bh*NN + m)*KWW + n] = acc[i][j]*0.125f;
        }
    }
}

// ---------------------------------------------------------------------------
// y[bh,k,d] = sum_n P[bh,n,k] * v[b,n,h,d]   (P = post-softmax S2)
__global__ void yv_kernel(const float* __restrict__ S, const float* __restrict__ qkv,
                          float* __restrict__ y) {
    int bh = blockIdx.y; int b = bh / HH, h = bh % HH;
    const float* A = S + (size_t)bh*NN*KWW;                       // [n][k]
    const float* V = qkv + (size_t)b*NN*3*CC + 2*CC + (size_t)h*DD; // row stride 3C
    float* Cy = y + (size_t)bh*KWW*DD;
    int bm = blockIdx.x * 64;   // k-tile
    __shared__ __align__(16) float As[16][68];
    __shared__ __align__(16) float Bs[16][68];
    int tid = threadIdx.x; int tx = tid & 15, ty = tid >> 4;
    float acc[4][4] = {};
    for (int n0 = 0; n0 < NN; n0 += 16) {
        #pragma unroll
        for (int i = tid; i < 1024; i += 256) {
            int nn = i >> 6, m = i & 63;
            float va = 0.f, vb = 0.f;
            if (n0+nn < NN && bm+m < KWW) va = A[(size_t)(n0+nn)*KWW + bm+m];
            if (n0+nn < NN)               vb = V[(size_t)(n0+nn)*3*CC + m];
            As[nn][m] = va;
            Bs[nn][m] = vb;
        }
        __syncthreads();
        #pragma unroll
        for (int kk = 0; kk < 16; kk++) {
            float4 a  = *(const float4*)&As[kk][ty*4];
            float4 bv = *(const float4*)&Bs[kk][tx*4];
            float aa[4] = {a.x,a.y,a.z,a.w};
            float bb[4] = {bv.x,bv.y,bv.z,bv.w};
            #pragma unroll
            for (int i = 0; i < 4; i++)
                #pragma unroll
                for (int j = 0; j < 4; j++) acc[i][j] += aa[i]*bb[j];
        }
        __syncthreads();
    }
    #pragma unroll
    for (int i = 0; i < 4; i++) {
        int m = bm + ty*4 + i; if (m >= KWW) continue;
        #pragma unroll
        for (int j = 0; j < 4; j++) Cy[(size_t)m*DD + tx*4 + j] = acc[i][j];
    }
}

// ---------------------------------------------------------------------------
// x1[b,n,h*64+d] += sum_k y[bh,k,d]*fc2_w[k,n] + fc2_b[n]
__global__ void fc2_kernel(const float* __restrict__ y, const float* __restrict__ w,
                           const float* __restrict__ bias, float* __restrict__ x1) {
    int bh = blockIdx.y; int b = bh / HH, h = bh % HH;
    const float* Y = y + (size_t)bh*KWW*DD;     // [k][d]
    float* Cx = x1 + (size_t)b*NN*CC + (size_t)h*DD; // row n stride C
    int bm = blockIdx.x * 64;   // n-token tile
    __shared__ __align__(16) float As[16][68];
    __shared__ __align__(16) float Bs[16][68];
    int tid = threadIdx.x; int tx = tid & 15, ty = tid >> 4;
    float acc[4][4] = {};
    for (int k0 = 0; k0 < KWW; k0 += 16) {
        #pragma unroll
        for (int i = tid; i < 1024; i += 256) {
            int kk = i >> 6, m = i & 63;
            float va = 0.f, vb = 0.f;
            if (k0+kk < KWW && bm+m < NN) va = w[(size_t)(k0+kk)*NN + bm+m];
            if (k0+kk < KWW)              vb = Y[(size_t)(k0+kk)*DD + m];
            As[kk][m] = va;
            Bs[kk][m] = vb;
        }
        __syncthreads();
        #pragma unroll
        for (int kk = 0; kk < 16; kk++) {
            float4 a  = *(const float4*)&As[kk][ty*4];
            float4 bv = *(const float4*)&Bs[kk][tx*4];
            float aa[4] = {a.x,a.y,a.z,a.w};
            float bb[4] = {bv.x,bv.y,bv.z,bv.w};
            #pragma unroll
            for (int i = 0; i < 4; i++)
                #pragma unroll
                for (int j = 0; j < 4; j++) acc[i][j] += aa[i]*bb[j];
        }
        __syncthreads();
    }
    #pragma unroll
    for (int i = 0; i < 4; i++) {
        int m = bm + ty*4 + i; if (m >= NN) continue;
        float bv = bias[m];
        #pragma unroll
        for (int j = 0; j < 4; j++) Cx[(size_t)m*CC + tx*4 + j] += acc[i][j] + bv;
    }
}

// ---------------------------------------------------------------------------
__global__ void init_kernel(const float* __restrict__ x, float* __restrict__ x1,
                            float* __restrict__ x2, int n) {
    int i = blockIdx.x*256 + threadIdx.x;
    if (i < n) { float v = x[i]; x1[i] = v; x2[i] = v; }
}
__global__ void final_kernel(const float* __restrict__ x1, const float* __restrict__ x2,
                             float* __restrict__ o, int n) {
    int i = blockIdx.x*256 + threadIdx.x;
    if (i < n) o[i] = 0.5f*(x1[i]+x2[i]);
}

// ---------------------------------------------------------------------------
extern "C" void kernel_launch(void* const* d_in, const int* in_sizes, int n_in,
                              void* d_out, int out_size, void* d_ws, size_t ws_size,
                              hipStream_t stream) {
    const float* x     = (const float*)d_in[0];
    const float* qkv_w = (const float*)d_in[1];
    const float* fc_w  = (const float*)d_in[2];
    const float* fc_b  = (const float*)d_in[3];
    const float* alng  = (const float*)d_in[4];
    const float* alnb  = (const float*)d_in[5];
    const float* fc2w  = (const float*)d_in[6];
    const float* fc2b  = (const float*)d_in[7];
    const float* w1    = (const float*)d_in[8];
    const float* b1    = (const float*)d_in[9];
    const float* w2    = (const float*)d_in[10];
    const float* b2    = (const float*)d_in[11];
    const float* flng  = (const float*)d_in[12];
    const float* flnb  = (const float*)d_in[13];
    const float* glng  = (const float*)d_in[14];
    const float* glnb  = (const float*)d_in[15];
    float* out = (float*)d_out;

    float* ws = (float*)d_ws;
    size_t off = 0;
    float* x1   = ws + off; off += (size_t)RR*CC;
    float* x2   = ws + off; off += (size_t)RR*CC;
    unsigned short* lnb = (unsigned short*)(ws + off); off += (size_t)RR*CC/2;
    float* qkvb = ws + off; off += (size_t)RR*3*CC;
    float* S1   = ws + off; off += (size_t)BHH*NN*KWW;
    float* S2   = ws + off; off += (size_t)BHH*NN*KWW;
    float* yb   = ws + off; off += (size_t)BHH*KWW*DD;
    unsigned short* qkv_wt = (unsigned short*)(ws + off); off += (size_t)3*CC*CC/2;
    unsigned short* w1t    = (unsigned short*)(ws + off); off += (size_t)CC*HIDD/2;
    unsigned short* w2t    = (unsigned short*)(ws + off); off += (size_t)CC*HIDD/2;
    unsigned short* hid = (unsigned short*)S1;  // alias: hid (9.7M fl) < S1 (14.9M fl)

    // --- weight prep: bf16 transposed copies (once per launch, ~50 us) ---
    transpose_cast<<<dim3(3*CC/32, CC/32), 256, 0, stream>>>(qkv_w, qkv_wt, CC, 3*CC);
    transpose_cast<<<dim3(HIDD/32, CC/32), 256, 0, stream>>>(w1, w1t, CC, HIDD);
    transpose_cast<<<dim3(CC/32, HIDD/32), 256, 0, stream>>>(w2, w2t, HIDD, CC);

    const int nel = RR*CC;
    init_kernel<<<(nel+255)/256, 256, 0, stream>>>(x, x1, x2, nel);

    const int MT = (RR + 127) / 128;   // 50 row-tiles
    for (int l = 0; l < NL; l++) {
        // --- attention branch: y1 = x1 + attn(LN(x2)) ---
        ln768_kernel<<<RR, 256, 0, stream>>>(x2, flng + l*CC, flnb + l*CC, lnb);
        gemm_bf16<0><<<dim3(3*CC/128, MT), 256, 0, stream>>>(
            lnb, qkv_wt, nullptr, qkvb, nullptr, RR, 3*CC, CC);
        qk_kernel<<<dim3(4, 4, BHH), 256, 0, stream>>>(qkvb, S1);
        gemm_kernel<1><<<dim3(4, 4, BHH), 256, 0, stream>>>(
            S1, (long)NN*KWW, fc_w, fc_b, S2, (long)NN*KWW, NN, KWW, NN);
        lnsoftmax_kernel<<<(BHH*NN)/4, 256, 0, stream>>>(S2, alng, alnb);
        yv_kernel<<<dim3(4, BHH), 256, 0, stream>>>(S2, qkvb, yb);
        fc2_kernel<<<dim3(4, BHH), 256, 0, stream>>>(yb, fc2w, fc2b, x1);
        // --- mlp branch: y2 = x2 + mlp(LN(y1)) ---
        ln768_kernel<<<RR, 256, 0, stream>>>(x1, glng + l*CC, glnb + l*CC, lnb);
        gemm_bf16<2><<<dim3(HIDD/128, MT), 256, 0, stream>>>(
            lnb, w1t, b1, nullptr, hid, RR, HIDD, CC);
        gemm_bf16<3><<<dim3(CC/128, MT), 256, 0, stream>>>(
            hid, w2t, b2, x2, nullptr, RR, CC, HIDD);
    }
    final_kernel<<<(nel+255)/256, 256, 0, stream>>>(x1, x2, out, nel);
}

// Round 3
// 4856.955 us; speedup vs baseline: 4.7030x; 1.6386x over previous
//
#include <hip/hip_runtime.h>
#include <math.h>

// Problem constants
#define BB   32
#define NN   197
#define CC   768
#define HH   12
#define DD   64
#define KWW  197
#define HIDD 3072
#define NL   12
#define RR   (BB*NN)      // 6304 rows
#define BHH  (BB*HH)      // 384 batch*head
#define NP   224          // n/kw padded to multiple of 32 (for MFMA K dim)

typedef __attribute__((ext_vector_type(8))) short short8;
typedef __attribute__((ext_vector_type(4))) float floatx4;
typedef __attribute__((ext_vector_type(4))) unsigned short us4;

__device__ __forceinline__ unsigned short f2bf(float f) {
    unsigned int u = __float_as_uint(f);
    u += 0x7fff + ((u >> 16) & 1);          // round-to-nearest-even
    return (unsigned short)(u >> 16);
}

// ---------------------------------------------------------------------------
// LayerNorm over C=768 -> bf16 output. One block (256 thr) per row.
__global__ void ln768_kernel(const float* __restrict__ in, const float* __restrict__ g,
                             const float* __restrict__ be, unsigned short* __restrict__ out) {
    int row = blockIdx.x;
    const float* x = in + (size_t)row * CC;
    unsigned short* o = out + (size_t)row * CC;
    int t = threadIdx.x;
    float v0 = x[t], v1 = x[t+256], v2 = x[t+512];
    float s = v0+v1+v2;
    float q = v0*v0+v1*v1+v2*v2;
    for (int off = 1; off < 64; off <<= 1) {
        s += __shfl_xor(s, off, 64);
        q += __shfl_xor(q, off, 64);
    }
    __shared__ float sh[8];
    int wv = t >> 6, ln = t & 63;
    if (ln == 0) { sh[wv] = s; sh[4+wv] = q; }
    __syncthreads();
    s = sh[0]+sh[1]+sh[2]+sh[3];
    q = sh[4]+sh[5]+sh[6]+sh[7];
    float mu  = s * (1.0f/CC);
    float var = q * (1.0f/CC) - mu*mu;
    float rs  = rsqrtf(var + 1e-5f);
    o[t]     = f2bf((v0-mu)*rs*g[t]     + be[t]);
    o[t+256] = f2bf((v1-mu)*rs*g[t+256] + be[t+256]);
    o[t+512] = f2bf((v2-mu)*rs*g[t+512] + be[t+512]);
}

// ---------------------------------------------------------------------------
// Transpose + cast fp32 [K][Nd] -> bf16 [Nd][Kpad], zero-filling k in [K,Kpad).
__global__ void transpose_cast(const float* __restrict__ in, unsigned short* __restrict__ out,
                               int K, int Nd, int Kpad) {
    __shared__ float tile[32][33];
    int n0 = blockIdx.x*32, k0 = blockIdx.y*32;
    int tx = threadIdx.x & 31, ty = threadIdx.x >> 5;   // 32 x 8
    #pragma unroll
    for (int i = 0; i < 4; i++) {
        int k = k0 + ty + i*8;
        tile[ty + i*8][tx] = (k < K && n0+tx < Nd) ? in[(size_t)k*Nd + n0 + tx] : 0.f;
    }
    __syncthreads();
    #pragma unroll
    for (int i = 0; i < 4; i++) {
        int n = n0 + ty + i*8;
        if (n < Nd && k0 + tx < Kpad) out[(size_t)n*Kpad + k0 + tx] = f2bf(tile[tx][ty + i*8]);
    }
}

// ---------------------------------------------------------------------------
// bf16 MFMA GEMM: C = A(bf16,[M][K]) @ Bt(bf16,[Nd][K])^T. 128x128 tile, BK=32.
// EPI: 2 = +bias exact-GELU store bf16; 3 = +bias accumulate fp32;
//      4 = QKV epilogue: scatter bf16 into q[bh][n][d], k[bh][n][d], vT[bh][d][NP]
template<int EPI>
__global__ __launch_bounds__(256) void gemm_bf16(
    const unsigned short* __restrict__ A, const unsigned short* __restrict__ Bt,
    const float* __restrict__ bias, float* __restrict__ Cf, unsigned short* __restrict__ Cb,
    int M, int Nd, int K)
{
    __shared__ unsigned short As[128*32];
    __shared__ unsigned short Bs[128*32];
    int tid  = threadIdx.x;
    int wv   = tid >> 6, lane = tid & 63;
    int wm   = wv >> 1, wn = wv & 1;
    int bm   = blockIdx.y * 128, bn = blockIdx.x * 128;
    int quad = lane >> 4, mrow = lane & 15;
    int srow = lane >> 2;            // staging: 4 lanes per 32-elem row
    int skof = (lane & 3) * 8;       // 8 bf16 = 16B per lane
    floatx4 acc[4][4];
    #pragma unroll
    for (int i = 0; i < 4; i++)
        #pragma unroll
        for (int j = 0; j < 4; j++) acc[i][j] = (floatx4){0.f,0.f,0.f,0.f};

    for (int k0 = 0; k0 < K; k0 += 32) {
        #pragma unroll
        for (int i = 0; i < 2; i++) {
            int r  = wv*32 + i*16 + srow;
            int gr = bm + r; if (gr > M-1) gr = M-1;
            __builtin_amdgcn_global_load_lds(
                (const __attribute__((address_space(1))) void*)(A + (size_t)gr*K + k0 + skof),
                (__attribute__((address_space(3))) void*)(As + (wv*32 + i*16)*32),
                16, 0, 0);
            __builtin_amdgcn_global_load_lds(
                (const __attribute__((address_space(1))) void*)(Bt + (size_t)(bn + r)*K + k0 + skof),
                (__attribute__((address_space(3))) void*)(Bs + (wv*32 + i*16)*32),
                16, 0, 0);
        }
        __syncthreads();
        short8 af[4], bf[4];
        #pragma unroll
        for (int mi = 0; mi < 4; mi++)
            af[mi] = *(const short8*)&As[(wm*64 + mi*16 + mrow)*32 + quad*8];
        #pragma unroll
        for (int ni = 0; ni < 4; ni++)
            bf[ni] = *(const short8*)&Bs[(wn*64 + ni*16 + mrow)*32 + quad*8];
        #pragma unroll
        for (int mi = 0; mi < 4; mi++)
            #pragma unroll
            for (int ni = 0; ni < 4; ni++)
                acc[mi][ni] = __builtin_amdgcn_mfma_f32_16x16x32_bf16(af[mi], bf[ni], acc[mi][ni], 0, 0, 0);
        __syncthreads();
    }

    #pragma unroll
    for (int mi = 0; mi < 4; mi++) {
        int row0 = bm + wm*64 + mi*16 + quad*4;
        #pragma unroll
        for (int ni = 0; ni < 4; ni++) {
            int col = bn + wn*64 + ni*16 + mrow;
            float bv = (EPI == 2 || EPI == 3) ? bias[col] : 0.f;
            #pragma unroll
            for (int r = 0; r < 4; r++) {
                int row = row0 + r;
                if (row >= M) continue;
                float v = acc[mi][ni][r] + bv;
                if (EPI == 2) {
                    v = 0.5f*v*(1.0f + erff(v*0.70710678118f));
                    Cb[(size_t)row*Nd + col] = f2bf(v);
                } else if (EPI == 3) {
                    Cf[(size_t)row*Nd + col] += v;
                } else if (EPI == 4) {
                    int sel = col / CC;
                    int rem = col - sel*CC;
                    int h = rem >> 6, d = rem & 63;
                    int b = row / NN, n = row - b*NN;
                    int bh = b*HH + h;
                    unsigned short val = f2bf(v);
                    if (sel < 2)
                        Cb[((size_t)sel*BHH + bh)*NN*DD + (size_t)n*DD + d] = val;
                    else
                        Cb[(size_t)2*BHH*NN*DD + (size_t)bh*DD*NP + (size_t)d*NP + n] = val;
                } else {
                    Cf[(size_t)row*Nd + col] = v;
                }
            }
        }
    }
}

// ---------------------------------------------------------------------------
// Batched bf16 MFMA GEMM over blockIdx.z = bh.
// C[M][Nd] = A[M][K] @ Bt[Nd][K]^T per batch. Waves: (4/WGN) x WGN grid,
// each wave WMxWN MFMAs of 16x16x32.  BM = (4/WGN)*WM*16, BN = WGN*WN*16.
// EPI: 0 = scale, store bf16 [row][col] (qk -> S1bf)
//      1 = +bias[col], store fp32 [row][col] (fc -> S2f)
//      2 = store bf16 TRANSPOSED [col][row]  (yv -> yT)
//      3 = +bias[row], accumulate fp32 into x1 at (b,n,h*64+d) (fc2)
template<int BM, int BN, int WM, int WN, int WGN, int EPI>
__global__ __launch_bounds__(256) void bgemm(
    const unsigned short* __restrict__ A, long Az, int lda,
    const unsigned short* __restrict__ Bt, long Bz, int ldb,
    const float* __restrict__ bias,
    float* __restrict__ Cf, unsigned short* __restrict__ Cb, long Cz, int ldc,
    int M, int Nd, int K, float scale)
{
    int bh = blockIdx.z;
    const unsigned short* Ab = A  + (size_t)bh*Az;
    const unsigned short* Bb = Bt + (size_t)bh*Bz;
    __shared__ unsigned short As[BM*32];
    __shared__ unsigned short Bs[BN*32];
    int tid  = threadIdx.x;
    int wv   = tid >> 6, lane = tid & 63;
    int wm   = wv / WGN, wn = wv % WGN;
    int bm   = blockIdx.y * BM, bn = blockIdx.x * BN;
    int quad = lane >> 4, mrow = lane & 15;
    int srow = lane >> 2;
    int skof = (lane & 3) * 8;
    floatx4 acc[WM][WN];
    #pragma unroll
    for (int i = 0; i < WM; i++)
        #pragma unroll
        for (int j = 0; j < WN; j++) acc[i][j] = (floatx4){0.f,0.f,0.f,0.f};

    for (int k0 = 0; k0 < K; k0 += 32) {
        #pragma unroll
        for (int i = 0; i < BM/64; i++) {
            int r  = wv*(BM/4) + i*16 + srow;
            int gr = bm + r; if (gr > M-1) gr = M-1;
            __builtin_amdgcn_global_load_lds(
                (const __attribute__((address_space(1))) void*)(Ab + (size_t)gr*lda + k0 + skof),
                (__attribute__((address_space(3))) void*)(As + (wv*(BM/4) + i*16)*32),
                16, 0, 0);
        }
        #pragma unroll
        for (int i = 0; i < BN/64; i++) {
            int r  = wv*(BN/4) + i*16 + srow;
            int gr = bn + r; if (gr > Nd-1) gr = Nd-1;
            __builtin_amdgcn_global_load_lds(
                (const __attribute__((address_space(1))) void*)(Bb + (size_t)gr*ldb + k0 + skof),
                (__attribute__((address_space(3))) void*)(Bs + (wv*(BN/4) + i*16)*32),
                16, 0, 0);
        }
        __syncthreads();
        short8 af[WM], bf[WN];
        #pragma unroll
        for (int mi = 0; mi < WM; mi++)
            af[mi] = *(const short8*)&As[(wm*WM*16 + mi*16 + mrow)*32 + quad*8];
        #pragma unroll
        for (int ni = 0; ni < WN; ni++)
            bf[ni] = *(const short8*)&Bs[(wn*WN*16 + ni*16 + mrow)*32 + quad*8];
        #pragma unroll
        for (int mi = 0; mi < WM; mi++)
            #pragma unroll
            for (int ni = 0; ni < WN; ni++)
                acc[mi][ni] = __builtin_amdgcn_mfma_f32_16x16x32_bf16(af[mi], bf[ni], acc[mi][ni], 0, 0, 0);
        __syncthreads();
    }

    #pragma unroll
    for (int mi = 0; mi < WM; mi++) {
        int row0 = bm + wm*WM*16 + mi*16 + quad*4;
        #pragma unroll
        for (int ni = 0; ni < WN; ni++) {
            int col = bn + wn*WN*16 + ni*16 + mrow;
            #pragma unroll
            for (int r = 0; r < 4; r++) {
                int row = row0 + r;
                float v = acc[mi][ni][r];
                if (EPI == 0) {
                    if (row < M && col < Nd)
                        Cb[(size_t)bh*Cz + (size_t)row*ldc + col] = f2bf(v*scale);
                } else if (EPI == 1) {
                    if (row < M && col < Nd)
                        Cf[(size_t)bh*Cz + (size_t)row*ldc + col] = v + bias[col];
                } else if (EPI == 2) {
                    if (row < M)
                        Cb[(size_t)bh*Cz + (size_t)col*ldc + row] = f2bf(v);
                } else {
                    if (row < M) {
                        int b = bh / HH, h = bh - b*HH;
                        Cf[(size_t)b*NN*CC + (size_t)h*DD + (size_t)row*CC + col] += v + bias[row];
                    }
                }
            }
        }
    }
}

// ---------------------------------------------------------------------------
// Fused LayerNorm + softmax over KW=197, writing P TRANSPOSED in bf16:
// PT[bh][kw][n] (n padded to NP). Block = 4 waves = 4 consecutive rows n.
__global__ void lnsoftmax_t(const float* __restrict__ S, const float* __restrict__ g,
                            const float* __restrict__ be, unsigned short* __restrict__ PT) {
    int bh = blockIdx.x / 50;
    int n0 = (blockIdx.x - bh*50) * 4;
    int wv = threadIdx.x >> 6, lane = threadIdx.x & 63;
    int n = n0 + wv;
    __shared__ unsigned short tile[4][NP];
    bool valid = (n < NN);
    float v[4];
    if (valid) {
        const float* p = S + ((size_t)bh*NN + n)*KWW;
        float s = 0.f, q = 0.f;
        #pragma unroll
        for (int t = 0; t < 4; t++) {
            int k = lane + t*64;
            float x = (k < KWW) ? p[k] : 0.f;
            v[t] = x; s += x; q += x*x;
        }
        for (int o = 1; o < 64; o <<= 1) { s += __shfl_xor(s, o, 64); q += __shfl_xor(q, o, 64); }
        float mu  = s * (1.0f/KWW);
        float var = q * (1.0f/KWW) - mu*mu;
        float rs  = rsqrtf(var + 1e-5f);
        float mx = -1e30f;
        #pragma unroll
        for (int t = 0; t < 4; t++) {
            int k = lane + t*64;
            if (k < KWW) { v[t] = (v[t]-mu)*rs*g[k] + be[k]; mx = fmaxf(mx, v[t]); }
        }
        for (int o = 1; o < 64; o <<= 1) mx = fmaxf(mx, __shfl_xor(mx, o, 64));
        float se = 0.f;
        #pragma unroll
        for (int t = 0; t < 4; t++) {
            int k = lane + t*64;
            if (k < KWW) { v[t] = expf(v[t]-mx); se += v[t]; }
        }
        for (int o = 1; o < 64; o <<= 1) se += __shfl_xor(se, o, 64);
        float inv = 1.0f / se;
        #pragma unroll
        for (int t = 0; t < 4; t++) v[t] *= inv;
    }
    #pragma unroll
    for (int t = 0; t < 4; t++) {
        int k = lane + t*64;
        if (k < KWW) tile[wv][k] = valid ? f2bf(v[t]) : (unsigned short)0;
    }
    __syncthreads();
    int kw = threadIdx.x;
    if (kw < KWW) {
        us4 o = { tile[0][kw], tile[1][kw], tile[2][kw], tile[3][kw] };
        *(us4*)&PT[((size_t)bh*NN + kw)*NP + n0] = o;
    }
}

// ---------------------------------------------------------------------------
__global__ void init_kernel(const float* __restrict__ x, float* __restrict__ x1,
                            float* __restrict__ x2, int n) {
    int i = blockIdx.x*256 + threadIdx.x;
    if (i < n) { float v = x[i]; x1[i] = v; x2[i] = v; }
}
__global__ void final_kernel(const float* __restrict__ x1, const float* __restrict__ x2,
                             float* __restrict__ o, int n) {
    int i = blockIdx.x*256 + threadIdx.x;
    if (i < n) o[i] = 0.5f*(x1[i]+x2[i]);
}

// ---------------------------------------------------------------------------
extern "C" void kernel_launch(void* const* d_in, const int* in_sizes, int n_in,
                              void* d_out, int out_size, void* d_ws, size_t ws_size,
                              hipStream_t stream) {
    const float* x     = (const float*)d_in[0];
    const float* qkv_w = (const float*)d_in[1];
    const float* fc_w  = (const float*)d_in[2];
    const float* fc_b  = (const float*)d_in[3];
    const float* alng  = (const float*)d_in[4];
    const float* alnb  = (const float*)d_in[5];
    const float* fc2w  = (const float*)d_in[6];
    const float* fc2b  = (const float*)d_in[7];
    const float* w1    = (const float*)d_in[8];
    const float* b1    = (const float*)d_in[9];
    const float* w2    = (const float*)d_in[10];
    const float* b2    = (const float*)d_in[11];
    const float* flng  = (const float*)d_in[12];
    const float* flnb  = (const float*)d_in[13];
    const float* glng  = (const float*)d_in[14];
    const float* glnb  = (const float*)d_in[15];
    float* out = (float*)d_out;

    float* ws = (float*)d_ws;
    size_t off = 0;
    float* x1 = ws + off; off += (size_t)RR*CC;
    float* x2 = ws + off; off += (size_t)RR*CC;
    unsigned short* lnb = (unsigned short*)(ws + off); off += (size_t)RR*CC/2;
    // qkv bf16 region: q[bh][n][64], k[bh][n][64], vT[bh][64][NP]
    unsigned short* qkvo = (unsigned short*)(ws + off);
    unsigned short* qb = qkvo;
    unsigned short* kb = qkvo + (size_t)BHH*NN*DD;
    unsigned short* vT = qkvo + (size_t)2*BHH*NN*DD;
    off += ((size_t)2*BHH*NN*DD + (size_t)BHH*DD*NP) / 2;
    unsigned short* S1bf = (unsigned short*)(ws + off); off += (size_t)BHH*NN*NP/2;
    unsigned short* PT   = (unsigned short*)(ws + off); off += (size_t)BHH*NN*NP/2;
    unsigned short* yT   = (unsigned short*)(ws + off); off += (size_t)BHH*DD*NP/2;
    float* S2f = ws + off; off += (size_t)BHH*NN*KWW;
    unsigned short* qkv_wt = (unsigned short*)(ws + off); off += (size_t)3*CC*CC/2;
    unsigned short* w1t    = (unsigned short*)(ws + off); off += (size_t)CC*HIDD/2;
    unsigned short* w2t    = (unsigned short*)(ws + off); off += (size_t)CC*HIDD/2;
    unsigned short* fc_wt  = (unsigned short*)(ws + off); off += (size_t)KWW*NP/2 + 16;
    unsigned short* fc2_wt = (unsigned short*)(ws + off); off += (size_t)KWW*NP/2 + 16;
    unsigned short* hid = (unsigned short*)S2f;  // alias: hid (19.4M ush) < S2f (14.9M fl)

    // Zero padded bf16 region (vT..yT contiguous) so K-pads read as 0.
    size_t zero_bytes = ((size_t)BHH*DD*NP + (size_t)2*BHH*NN*NP + (size_t)BHH*DD*NP) * 2;
    hipMemsetAsync(vT, 0, zero_bytes, stream);

    // Weight prep: bf16 transposed (+padded) copies, once per launch.
    transpose_cast<<<dim3(72, 24), 256, 0, stream>>>(qkv_w, qkv_wt, CC, 3*CC, CC);
    transpose_cast<<<dim3(96, 24), 256, 0, stream>>>(w1, w1t, CC, HIDD, CC);
    transpose_cast<<<dim3(24, 96), 256, 0, stream>>>(w2, w2t, HIDD, CC, HIDD);
    transpose_cast<<<dim3(7, 7),   256, 0, stream>>>(fc_w,  fc_wt,  NN, KWW, NP);
    transpose_cast<<<dim3(7, 7),   256, 0, stream>>>(fc2w,  fc2_wt, KWW, NN, NP);

    const int nel = RR*CC;
    init_kernel<<<(nel+255)/256, 256, 0, stream>>>(x, x1, x2, nel);

    const int MT = (RR + 127) / 128;   // 50 row-tiles
    for (int l = 0; l < NL; l++) {
        // --- attention branch: y1 = x1 + attn(LN(x2)) ---
        ln768_kernel<<<RR, 256, 0, stream>>>(x2, flng + l*CC, flnb + l*CC, lnb);
        gemm_bf16<4><<<dim3(3*CC/128, MT), 256, 0, stream>>>(
            lnb, qkv_wt, nullptr, nullptr, qb, RR, 3*CC, CC);
        // S1 = scale * Q @ K^T   -> bf16 [bh][197][NP]
        bgemm<128,128,4,4,2,0><<<dim3(2, 2, BHH), 256, 0, stream>>>(
            qb, (long)NN*DD, DD, kb, (long)NN*DD, DD, nullptr,
            nullptr, S1bf, (long)NN*NP, NP, NN, NN, DD, 0.125f);
        // S2 = S1 @ fc_w + fc_b  -> fp32 [bh][197][197]
        bgemm<128,128,4,4,2,1><<<dim3(2, 2, BHH), 256, 0, stream>>>(
            S1bf, (long)NN*NP, NP, fc_wt, 0, NP, fc_b,
            S2f, nullptr, (long)NN*KWW, KWW, NN, NN, NP, 1.f);
        // P^T (bf16, padded) = softmax(LN(S2))^T
        lnsoftmax_t<<<BHH*50, 256, 0, stream>>>(S2f, alng, alnb, PT);
        // yT[d][kw] = (P^T @ V)^T  -> bf16 [bh][64][NP]
        bgemm<128,64,2,4,1,2><<<dim3(1, 2, BHH), 256, 0, stream>>>(
            PT, (long)NN*NP, NP, vT, (long)DD*NP, NP, nullptr,
            nullptr, yT, (long)DD*NP, NP, NN, DD, NP, 1.f);
        // x1[b,n,h*64+d] += fc2_wt[n][kw] . yT[d][kw] + fc2_b[n]
        bgemm<128,64,2,4,1,3><<<dim3(1, 2, BHH), 256, 0, stream>>>(
            fc2_wt, 0, NP, yT, (long)DD*NP, NP, fc2b,
            x1, nullptr, 0, 0, NN, DD, NP, 1.f);
        // --- mlp branch: y2 = x2 + mlp(LN(y1)) ---
        ln768_kernel<<<RR, 256, 0, stream>>>(x1, glng + l*CC, glnb + l*CC, lnb);
        gemm_bf16<2><<<dim3(HIDD/128, MT), 256, 0, stream>>>(
            lnb, w1t, b1, nullptr, hid, RR, HIDD, CC);
        gemm_bf16<3><<<dim3(CC/128, MT), 256, 0, stream>>>(
            hid, w2t, b2, x2, nullptr, RR, CC, HIDD);
    }
    final_kernel<<<(nel+255)/256, 256, 0, stream>>>(x1, x2, out, nel);
}